// Round 8
// baseline (2674.512 us; speedup 1.0000x reference)
//
#include <hip/hip_runtime.h>
#include <math.h>

#define B_      4
#define F_BINS  128
#define T_FULL  16384
#define KF      33
#define KT      129

// conv tile geometry: 32 f-planes x 128 t per block, 4 waves (32 t each)
#define TT      128
#define ROWS    260                // TT + halo
#define PITCH   72                 // ushort pitch for 64 f cols
#define DTP     132                // padded dt rows in wq (129 + prefetch pad)
#define D2      48                 // padded d2 (df) window

typedef __attribute__((ext_vector_type(8)))  short short8;
typedef __attribute__((ext_vector_type(16))) float f32x16;
typedef uint uint4a16 __attribute__((ext_vector_type(4), aligned(16)));

union ABFrag { uint4a16 u; short8 v; };

__device__ __forceinline__ ushort f2bf(float v) {
  unsigned u = __float_as_uint(v);
  unsigned r = (u + 0x7FFFu + ((u >> 16) & 1u)) >> 16;
  return (ushort)r;
}

__device__ __forceinline__ short8 load_a16(const ushort* p) {
  ABFrag f; f.u = *(const uint4a16*)p; return f.v;
}

__device__ __forceinline__ short8 mkG(short8 a, short8 b) {
  return __builtin_shufflevector(a, b, 4, 5, 6, 7, 8, 9, 10, 11);
}

// ---------------------------------------------------------------------------
// prep_w: wq[oct 4][gam 2][ps 2][ch 16][dt 132][d2 48]
//         = wav[ch][df = d2 - 4 - gam - 2*ps][dt]   (zero-padded)
// ---------------------------------------------------------------------------
__global__ __launch_bounds__(256) void prep_w(
    const float* __restrict__ wr, const float* __restrict__ wi,
    ushort* __restrict__ wq) {
  int idx = blockIdx.x * 256 + threadIdx.x;      // 4*2*2*16*132*48 = 1622016
  int d2  = idx % D2;
  int dt  = (idx / D2) % DTP;
  int ch  = (idx / (D2 * DTP)) % 16;
  int ps  = (idx / (D2 * DTP * 16)) % 2;
  int gam = (idx / (D2 * DTP * 16 * 2)) % 2;
  int oct = idx / (D2 * DTP * 16 * 2 * 2);
  int df  = d2 - 4 - gam - 2 * ps;
  float v = 0.f;
  if (df >= 0 && df < KF && dt < KT) {
    const float* src = (ch < 8) ? wr : wi;
    v = src[(((size_t)oct * 8 + (ch & 7)) * KF + df) * KT + dt];
  }
  wq[idx] = f2bf(v);
}

// ---------------------------------------------------------------------------
// prep_x: bf16 transposed pyramid  xTj[b][T_j][128f]  for j=0..3
// ---------------------------------------------------------------------------
__global__ __launch_bounds__(256) void prep_x(
    const float* __restrict__ x,
    ushort* __restrict__ xT0, ushort* __restrict__ xT1,
    ushort* __restrict__ xT2, ushort* __restrict__ xT3) {
  __shared__ float lt[128 * 65];
  const int b  = blockIdx.y;
  const int t0 = blockIdx.x * 64;
  const int tid = threadIdx.x;
  const int wv = tid >> 6, lane = tid & 63;
#pragma unroll
  for (int rep = 0; rep < 32; ++rep) {
    int f = rep * 4 + wv;
    lt[f * 65 + lane] = x[((size_t)b * 128 + f) * T_FULL + t0 + lane];
  }
  __syncthreads();
  ushort* dst[4] = {xT0, xT1, xT2, xT3};
  const int Ts[4] = {16384, 8192, 4096, 2048};
  for (int lvl = 0; lvl < 4; ++lvl) {
    int nt = 64 >> lvl, w = 1 << lvl;
    float inv = 1.f / (float)w;
    int tasks = nt * 16;
    for (int i = tid; i < tasks; i += 256) {
      int tl = i >> 4, fc = i & 15;
      __align__(16) ushort vs[8];
#pragma unroll
      for (int e = 0; e < 8; ++e) {
        float a = 0.f;
        for (int m = 0; m < w; ++m) a += lt[(fc * 8 + e) * 65 + tl * w + m];
        vs[e] = f2bf(a * inv);
      }
      ushort* pdst = dst[lvl] + ((size_t)b * Ts[lvl] + (t0 >> lvl) + tl) * 128 + fc * 8;
      *(uint4*)pdst = *(const uint4*)vs;
    }
  }
}

// ---------------------------------------------------------------------------
// conv_mfma: all octaves fused, 3840 equal-work blocks.
// MFMA 32x32x16_bf16: M=32=(ps2 x ch16), N=32 positions, K=16=(2dt x 8d2).
// Per (gam,kh) pass: 4 k-planes q: fo = f0 + gam + 16*kh + 4*q + 2*ps.
//   q0: A=G[s'], q1: A=F[s'] (s'<=4); q2: A=G[s'-1], q3: A=F[s'-1] (s'>=1)
// B-read column offset = (s' + 2*kh)*8. F rotated in place across c.
// Epilogue: re/im pairs are per-lane regs (acc[8ps+b], acc[8ps+4+b]).
// ---------------------------------------------------------------------------
__global__ __launch_bounds__(256, 3) void conv_mfma(
    const ushort* __restrict__ xT0, const ushort* __restrict__ xT1,
    const ushort* __restrict__ xT2, const ushort* __restrict__ xT3,
    const ushort* __restrict__ wq, float* __restrict__ out) {
  __shared__ ushort xt[ROWS * PITCH];
  const int tid = threadIdx.x;
  const int bx = blockIdx.x;

  int oct, local;
  if (bx < 2048)      { oct = 0; local = bx; }
  else if (bx < 3072) { oct = 1; local = bx - 2048; }
  else if (bx < 3584) { oct = 2; local = bx - 3072; }
  else                { oct = 3; local = bx - 3584; }
  const ushort* xT = (oct == 0) ? xT0 : (oct == 1) ? xT1 : (oct == 2) ? xT2 : xT3;
  const int Tj  = T_FULL >> oct;
  const int lw  = 4 - oct;                    // pool window = 1<<lw
  const int nxs = 7 - oct;
  const int tx   = local & ((1 << nxs) - 1);
  const int rest = local >> nxs;
  const int t0 = tx * TT;
  const int f0 = (rest & 3) * 32;
  const int b  = rest >> 2;

  // ---- stage transposed x tile: rows 0..259 (t = t0-64+row), cols f0-16+[0,64) ----
  for (int i = tid; i < ROWS * 8; i += 256) {
    int row = i >> 3, fc = i & 7;
    int t = t0 - 64 + row;
    int f = f0 - 16 + fc * 8;
    uint4 v = make_uint4(0u, 0u, 0u, 0u);
    if (t >= 0 && t < Tj && f >= 0 && f < 128)
      v = *(const uint4*)(xT + ((size_t)b * Tj + t) * 128 + f);
    *(uint4*)&xt[row * PITCH + fc * 8] = v;
  }
  __syncthreads();

  const int wave = tid >> 6, lane = tid & 63;
  const int n  = lane & 31;                // B col = t position
  const int h  = lane >> 5;                // k-half = dt sub-index; wavelet half
  const int ch = lane & 15;                // A row low = channel
  const int ps = (lane >> 4) & 1;          // A row high = +2 plane shift
  const float invw = 1.0f / (float)(1 << lw);

  for (int gam = 0; gam < 2; ++gam) {
    for (int kh = 0; kh < 2; ++kh) {
      const ushort* wp =
          wq + ((((size_t)((oct * 2 + gam) * 2 + ps)) * 16 + ch) * DTP + h) * D2;
      int rb = (32 * wave + n + h) * PITCH + 16 * kh;

      f32x16 acc[4];
#pragma unroll
      for (int q = 0; q < 4; ++q)
#pragma unroll
        for (int e = 0; e < 16; ++e) acc[q][e] = 0.f;

      short8 F[6];
#pragma unroll
      for (int u = 0; u < 6; ++u) F[u] = load_a16(wp + 8 * u);
      wp += 2 * D2;                        // points at c+1 block

#pragma unroll 1
      for (int c = 0; c < 65; ++c) {
        short8 G[5];
#pragma unroll
        for (int u = 0; u < 5; ++u) G[u] = mkG(F[u], F[u + 1]);
        __builtin_amdgcn_s_setprio(1);
#pragma unroll
        for (int s = 0; s < 6; ++s) {
          short8 bv = *(const short8*)&xt[rb + s * 8];
          if (s <= 4) {
            acc[0] = __builtin_amdgcn_mfma_f32_32x32x16_bf16(G[s], bv, acc[0], 0, 0, 0);
            acc[1] = __builtin_amdgcn_mfma_f32_32x32x16_bf16(F[s], bv, acc[1], 0, 0, 0);
          }
          if (s >= 1) {
            acc[2] = __builtin_amdgcn_mfma_f32_32x32x16_bf16(G[s - 1], bv, acc[2], 0, 0, 0);
            acc[3] = __builtin_amdgcn_mfma_f32_32x32x16_bf16(F[s - 1], bv, acc[3], 0, 0, 0);
          }
          // in-place prefetch of next-c fragments (F[u] dead after s'=u+1)
          if (s >= 2) F[s - 2] = load_a16(wp + 8 * (s - 2));
        }
        F[4] = load_a16(wp + 32);
        F[5] = load_a16(wp + 40);
        __builtin_amdgcn_s_setprio(0);
        wp += 2 * D2;                      // dt += 2
        rb += 2 * PITCH;                   // t row += 2
      }

      // ---- epilogue: per-lane modulus + pool butterfly + store ----
#pragma unroll
      for (int q = 0; q < 4; ++q) {
#pragma unroll
        for (int p2 = 0; p2 < 2; ++p2) {
          const int fo = f0 + gam + 16 * kh + 4 * q + 2 * p2;
#pragma unroll
          for (int bi = 0; bi < 4; ++bi) {
            float re = acc[q][8 * p2 + bi];
            float im = acc[q][8 * p2 + 4 + bi];
            float m = sqrtf(re * re + im * im);
            m += __shfl_xor(m, 1);
            if (lw >= 2) m += __shfl_xor(m, 2);
            if (lw >= 3) m += __shfl_xor(m, 4);
            if (lw >= 4) m += __shfl_xor(m, 8);
            if ((n & ((1 << lw) - 1)) == 0) {
              const int wvl = 4 * h + bi;
              const int tcol = (t0 + 32 * wave + n) >> lw;
              out[(((size_t)b * 32 + oct * 8 + wvl) * 128 + fo) * 1024 + tcol] =
                  m * invw;
            }
          }
        }
      }
    }
  }
}

// ---------------------------------------------------------------------------
extern "C" void kernel_launch(void* const* d_in, const int* in_sizes, int n_in,
                              void* d_out, int out_size, void* d_ws, size_t ws_size,
                              hipStream_t stream) {
  const float* x  = (const float*)d_in[0];
  const float* wr = (const float*)d_in[1];
  const float* wi = (const float*)d_in[2];
  float* out = (float*)d_out;

  ushort* xT0 = (ushort*)d_ws;                       // 4*16384*128
  ushort* xT1 = xT0 + (size_t)4 * 16384 * 128;       // 4*8192*128
  ushort* xT2 = xT1 + (size_t)4 * 8192 * 128;        // 4*4096*128
  ushort* xT3 = xT2 + (size_t)4 * 4096 * 128;        // 4*2048*128
  ushort* wq  = xT3 + (size_t)4 * 2048 * 128;        // 1622016

  prep_w<<<1622016 / 256, 256, 0, stream>>>(wr, wi, wq);
  prep_x<<<dim3(T_FULL / 64, B_), 256, 0, stream>>>(x, xT0, xT1, xT2, xT3);

  conv_mfma<<<3840, 256, 0, stream>>>(xT0, xT1, xT2, xT3, wq, out);
}

// Round 9
// 1948.278 us; speedup vs baseline: 1.3728x; 1.3728x over previous
//
#include <hip/hip_runtime.h>
#include <math.h>

#define B_      4
#define F_BINS  128
#define T_FULL  16384
#define KF      33
#define KT      129

// conv tile geometry: 32 f-planes x 128 t per block, 4 waves (32 t each)
#define TT      128
#define ROWS    260                // max row 256 + pad
#define PITCH   72                 // ushort pitch for 64 f cols (144B rows, 16B-aligned)
#define DTP     132                // padded dt rows in wq
#define D2      40                 // d2 (df) window: 5 fragments of 8

typedef __attribute__((ext_vector_type(8)))  short short8;
typedef __attribute__((ext_vector_type(16))) float f32x16;
typedef uint uint4a16 __attribute__((ext_vector_type(4), aligned(16)));

union ABFrag { uint4a16 u; short8 v; };

__device__ __forceinline__ ushort f2bf(float v) {
  unsigned u = __float_as_uint(v);
  unsigned r = (u + 0x7FFFu + ((u >> 16) & 1u)) >> 16;
  return (ushort)r;
}

__device__ __forceinline__ short8 load_a16(const ushort* p) {
  ABFrag f; f.u = *(const uint4a16*)p; return f.v;
}

// ---------------------------------------------------------------------------
// prep_w: wq[oct 4][rho 4][ps 2][ch 16][dt 132][d2 40]
//         = wav[ch][df = d2 - rho - 4*ps][dt]   (zero outside df/dt range)
// All output planes fo = f0 + rho + 4*ps + 8*k come from pure 8-aligned
// fragment shifts of this layout (no register concats needed).
// ---------------------------------------------------------------------------
__global__ __launch_bounds__(256) void prep_w(
    const float* __restrict__ wr, const float* __restrict__ wi,
    ushort* __restrict__ wq) {
  int idx = blockIdx.x * 256 + threadIdx.x;      // 4*4*2*16*132*40 = 2703360
  int d2  = idx % D2;
  int dt  = (idx / D2) % DTP;
  int ch  = (idx / (D2 * DTP)) % 16;
  int ps  = (idx / (D2 * DTP * 16)) % 2;
  int rho = (idx / (D2 * DTP * 16 * 2)) % 4;
  int oct = idx / (D2 * DTP * 16 * 2 * 4);
  int df  = d2 - rho - 4 * ps;
  float v = 0.f;
  if (df >= 0 && df < KF && dt < KT) {
    const float* src = (ch < 8) ? wr : wi;
    v = src[(((size_t)oct * 8 + (ch & 7)) * KF + df) * KT + dt];
  }
  wq[idx] = f2bf(v);
}

// ---------------------------------------------------------------------------
// prep_x: bf16 transposed pyramid  xTj[b][T_j][128f]  for j=0..3
// ---------------------------------------------------------------------------
__global__ __launch_bounds__(256) void prep_x(
    const float* __restrict__ x,
    ushort* __restrict__ xT0, ushort* __restrict__ xT1,
    ushort* __restrict__ xT2, ushort* __restrict__ xT3) {
  __shared__ float lt[128 * 65];
  const int b  = blockIdx.y;
  const int t0 = blockIdx.x * 64;
  const int tid = threadIdx.x;
  const int wv = tid >> 6, lane = tid & 63;
#pragma unroll
  for (int rep = 0; rep < 32; ++rep) {
    int f = rep * 4 + wv;
    lt[f * 65 + lane] = x[((size_t)b * 128 + f) * T_FULL + t0 + lane];
  }
  __syncthreads();
  ushort* dst[4] = {xT0, xT1, xT2, xT3};
  const int Ts[4] = {16384, 8192, 4096, 2048};
  for (int lvl = 0; lvl < 4; ++lvl) {
    int nt = 64 >> lvl, w = 1 << lvl;
    float inv = 1.f / (float)w;
    int tasks = nt * 16;
    for (int i = tid; i < tasks; i += 256) {
      int tl = i >> 4, fc = i & 15;
      __align__(16) ushort vs[8];
#pragma unroll
      for (int e = 0; e < 8; ++e) {
        float a = 0.f;
        for (int m = 0; m < w; ++m) a += lt[(fc * 8 + e) * 65 + tl * w + m];
        vs[e] = f2bf(a * inv);
      }
      ushort* pdst = dst[lvl] + ((size_t)b * Ts[lvl] + (t0 >> lvl) + tl) * 128 + fc * 8;
      *(uint4*)pdst = *(const uint4*)vs;
    }
  }
}

// ---------------------------------------------------------------------------
// conv_mfma: all octaves fused, 3840 equal-work blocks.
// MFMA 32x32x16_bf16: M=32=(ps2 x ch16), N=32 positions, K=16=(2dt x 8d2).
// Per rho pass (rho=0..3): 4 chains k=0..3, plane fo = f0 + rho + 4*ps + 8*k.
//   chain k active at s' in [k, k+4] with A = F[s'-k]  (pure fragment shift).
// B-read: 8 ds_read_b128 per c (cols 8s', s'=0..7), each feeds up to 4 MFMAs.
// A-stream triple-buffered (F0/F1/F2): loads issued 2 bodies before use.
// ---------------------------------------------------------------------------
__global__ __launch_bounds__(256, 3) void conv_mfma(
    const ushort* __restrict__ xT0, const ushort* __restrict__ xT1,
    const ushort* __restrict__ xT2, const ushort* __restrict__ xT3,
    const ushort* __restrict__ wq, float* __restrict__ out) {
  __shared__ ushort xt[ROWS * PITCH];
  const int tid = threadIdx.x;
  const int bx = blockIdx.x;

  int oct, local;
  if (bx < 2048)      { oct = 0; local = bx; }
  else if (bx < 3072) { oct = 1; local = bx - 2048; }
  else if (bx < 3584) { oct = 2; local = bx - 3072; }
  else                { oct = 3; local = bx - 3584; }
  const ushort* xT = (oct == 0) ? xT0 : (oct == 1) ? xT1 : (oct == 2) ? xT2 : xT3;
  const int Tj  = T_FULL >> oct;
  const int lw  = 4 - oct;                    // pool window = 1<<lw
  const int nxs = 7 - oct;
  const int tx   = local & ((1 << nxs) - 1);
  const int rest = local >> nxs;
  const int t0 = tx * TT;
  const int f0 = (rest & 3) * 32;
  const int b  = rest >> 2;

  // ---- stage transposed x tile: rows 0..259 (t = t0-64+row), cols f0-16+[0,64) ----
  for (int i = tid; i < ROWS * 8; i += 256) {
    int row = i >> 3, fc = i & 7;
    int t = t0 - 64 + row;
    int f = f0 - 16 + fc * 8;
    uint4 v = make_uint4(0u, 0u, 0u, 0u);
    if (t >= 0 && t < Tj && f >= 0 && f < 128)
      v = *(const uint4*)(xT + ((size_t)b * Tj + t) * 128 + f);
    *(uint4*)&xt[row * PITCH + fc * 8] = v;
  }
  __syncthreads();

  const int wave = tid >> 6, lane = tid & 63;
  const int n  = lane & 31;                // B col = t position
  const int h  = lane >> 5;                // k-half = dt sub-index; wavelet half
  const int ch = lane & 15;                // A row low = channel
  const int ps = (lane >> 4) & 1;          // A row high = +4 plane shift
  const float invw = 1.0f / (float)(1 << lw);

  for (int rho = 0; rho < 4; ++rho) {
    const ushort* wb =
        wq + ((((size_t)(oct * 4 + rho) * 2 + ps) * 16 + ch) * DTP + h) * D2;
    int rb = (32 * wave + n + h) * PITCH;

    f32x16 acc[4];
#pragma unroll
    for (int k = 0; k < 4; ++k)
#pragma unroll
      for (int e = 0; e < 16; ++e) acc[k][e] = 0.f;

    short8 F0[5], F1[5], F2[5];

    auto load5 = [](short8 (&F)[5], const ushort* ptr) {
#pragma unroll
      for (int u = 0; u < 5; ++u) F[u] = load_a16(ptr + 8 * u);
    };

    auto body = [&](short8 (&F)[5], int rbase) {
      __builtin_amdgcn_s_setprio(1);
#pragma unroll
      for (int s = 0; s < 8; ++s) {
        short8 bv = *(const short8*)&xt[rbase + s * 8];
#pragma unroll
        for (int kd = 0; kd < 4; ++kd) {
          const int k = 3 - kd;              // descending: max same-acc spacing
          if (k <= s && s - k <= 4)
            acc[k] = __builtin_amdgcn_mfma_f32_32x32x16_bf16(F[s - k], bv, acc[k], 0, 0, 0);
        }
      }
      __builtin_amdgcn_s_setprio(0);
    };

    // c-loop: 65 iterations (dt row pair per c), 3-stage pipeline, 63=21*3 + 2 tail
    load5(F0, wb);                     // c=0
    load5(F1, wb + 2 * D2);            // c=1
    const ushort* wp = wb;
#pragma unroll 1
    for (int cc = 0; cc < 21; ++cc) {
      load5(F2, wp + 4 * D2);  body(F0, rb);               // load c+2, run c
      load5(F0, wp + 6 * D2);  body(F1, rb + 2 * PITCH);   // load c+3, run c+1
      load5(F1, wp + 8 * D2);  body(F2, rb + 4 * PITCH);   // load c+4, run c+2
      wp += 6 * D2; rb += 6 * PITCH;
    }
    body(F0, rb);                      // c=63
    body(F1, rb + 2 * PITCH);          // c=64

    // ---- epilogue: per-lane modulus + pool butterfly + store ----
#pragma unroll
    for (int k = 0; k < 4; ++k) {
#pragma unroll
      for (int p2 = 0; p2 < 2; ++p2) {
        const int fo = f0 + rho + 4 * p2 + 8 * k;
#pragma unroll
        for (int bi = 0; bi < 4; ++bi) {
          float re = acc[k][8 * p2 + bi];
          float im = acc[k][8 * p2 + 4 + bi];
          float m = sqrtf(re * re + im * im);
          m += __shfl_xor(m, 1);
          if (lw >= 2) m += __shfl_xor(m, 2);
          if (lw >= 3) m += __shfl_xor(m, 4);
          if (lw >= 4) m += __shfl_xor(m, 8);
          if ((n & ((1 << lw) - 1)) == 0) {
            const int wvl = 4 * h + bi;
            const int tcol = (t0 + 32 * wave + n) >> lw;
            out[(((size_t)b * 32 + oct * 8 + wvl) * 128 + fo) * 1024 + tcol] =
                m * invw;
          }
        }
      }
    }
  }
}

// ---------------------------------------------------------------------------
extern "C" void kernel_launch(void* const* d_in, const int* in_sizes, int n_in,
                              void* d_out, int out_size, void* d_ws, size_t ws_size,
                              hipStream_t stream) {
  const float* x  = (const float*)d_in[0];
  const float* wr = (const float*)d_in[1];
  const float* wi = (const float*)d_in[2];
  float* out = (float*)d_out;

  ushort* xT0 = (ushort*)d_ws;                       // 4*16384*128
  ushort* xT1 = xT0 + (size_t)4 * 16384 * 128;       // 4*8192*128
  ushort* xT2 = xT1 + (size_t)4 * 8192 * 128;        // 4*4096*128
  ushort* xT3 = xT2 + (size_t)4 * 4096 * 128;        // 4*2048*128
  ushort* wq  = xT3 + (size_t)4 * 2048 * 128;        // 2703360

  prep_w<<<2703360 / 256, 256, 0, stream>>>(wr, wi, wq);
  prep_x<<<dim3(T_FULL / 64, B_), 256, 0, stream>>>(x, xT0, xT1, xT2, xT3);

  conv_mfma<<<3840, 256, 0, stream>>>(xT0, xT1, xT2, xT3, wq, out);
}